// Round 4
// baseline (3167.170 us; speedup 1.0000x reference)
//
#include <hip/hip_runtime.h>
#include <hip/hip_fp16.h>

// Problem constants
#define BATCH 64
#define TLEN  256
#define HD    512
#define G3    1536          // 3*H
#define KIN0  192           // folded conv+proj K = 64 bins * 3 taps
#define XT_S  258           // padded time slots (t' = -1 .. 256)
#define XT_STRIDE (XT_S*64) // per-batch stride in xT (16512)
#define NBLOCKS 96
#define NKS_HH 16           // HD/32 k-steps
#define NKS_I0 6            // KIN0/32 k-steps

typedef _Float16 f16;
typedef unsigned long long u64;
typedef __attribute__((ext_vector_type(8))) _Float16 half8;
typedef __attribute__((ext_vector_type(4))) float    f32x4;

__device__ __forceinline__ f32x4 mfma16(half8 a, half8 b, f32x4 c) {
    return __builtin_amdgcn_mfma_f32_16x16x32_f16(a, b, c, 0, 0, 0);
}

// Device-coherent (MALL) 16B load as two relaxed agent-scope u64 atomic loads.
__device__ __forceinline__ half8 loadA_sc1(const f16* p) {
    union { u64 v[2]; half8 h; } u;
    const u64* q = (const u64*)p;
    u.v[0] = __hip_atomic_load(q,     __ATOMIC_RELAXED, __HIP_MEMORY_SCOPE_AGENT);
    u.v[1] = __hip_atomic_load(q + 1, __ATOMIC_RELAXED, __HIP_MEMORY_SCOPE_AGENT);
    return u.h;
}

// ---------------- setup kernels ----------------

__global__ void fold_w3(const float* __restrict__ wih0,
                        const float* __restrict__ convw,
                        f16* __restrict__ w3) {
    int idx = blockIdx.x * 256 + threadIdx.x;
    if (idx >= G3 * KIN0) return;
    int g  = idx / KIN0;
    int kk = idx % KIN0;
    int dt = kk >> 6;
    int i  = kk & 63;
    float s = 0.f;
    for (int dr = 0; dr < 3; ++dr) {
        int r = i - dr;
        if (r < 0 || r >= 62) continue;
        const float* wrow = wih0 + (size_t)g * 3968 + r;
        #pragma unroll 8
        for (int f = 0; f < 64; ++f)
            s += wrow[f * 62] * convw[f * 9 + dr * 3 + dt];
    }
    w3[(size_t)g * KIN0 + kk] = (f16)s;
}

// wave-per-row: bias0[g] = b_ih0[g] + sum_e wih0[g,e] * convb[e/62]
__global__ void fold_bias0(const float* __restrict__ wih0,
                           const float* __restrict__ convb,
                           const float* __restrict__ bih0,
                           float* __restrict__ bias0) {
    int w    = (blockIdx.x * 256 + threadIdx.x) >> 6;
    int lane = threadIdx.x & 63;
    if (w >= G3) return;
    const float* wrow = wih0 + (size_t)w * 3968;
    float s = 0.f;
    for (int e = lane; e < 3968; e += 64) s += wrow[e] * convb[e / 62];
    #pragma unroll
    for (int o = 32; o > 0; o >>= 1) s += __shfl_down(s, o);
    if (lane == 0) bias0[w] = s + bih0[w];
}

struct Ptr5 { const float* p[5]; };

__global__ void cvt_weights(Ptr5 src, f16* __restrict__ dst) {
    int idx = blockIdx.x * 256 + threadIdx.x;
    if (idx >= 5 * G3 * HD) return;
    int m = idx / (G3 * HD), off = idx % (G3 * HD);
    dst[idx] = (f16)src.p[m][off];
}

// xT[b][s][i] = x[b, i, s-1] with zero pad at s=0 and s=257
__global__ void build_xt(const float* __restrict__ x, f16* __restrict__ xt) {
    int idx = blockIdx.x * 256 + threadIdx.x;
    if (idx >= BATCH * XT_S * 64) return;
    int b = idx / (XT_S * 64);
    int rem = idx % (XT_S * 64);
    int s = rem / 64, i = rem & 63;
    float v = 0.f;
    if (s >= 1 && s <= 256) v = x[(size_t)b * (64 * TLEN) + (size_t)i * TLEN + (s - 1)];
    xt[idx] = (f16)v;
}

// h(-1) lives at parity slot 1; also zero the grid-barrier counter.
__global__ void init_h(const float* __restrict__ h1, const float* __restrict__ h2,
                       const float* __restrict__ h3, f16* __restrict__ hbuf,
                       unsigned* __restrict__ bar) {
    int idx = blockIdx.x * 256 + threadIdx.x;
    const int HS = BATCH * HD;
    if (idx < 16) bar[idx] = 0u;
    if (idx >= HS) return;
    hbuf[1 * HS + idx] = (f16)h1[idx];
    hbuf[3 * HS + idx] = (f16)h2[idx];
    hbuf[5 * HS + idx] = (f16)h3[idx];
}

// ---------------- persistent diagonal-pipelined GRU ----------------
// Fragment-major LDS: frag(gate,ks,lane) at [((gate*NKS+ks)*64+lane)*8].
// Every wave ds_read_b128 is lane-sequential -> zero bank conflicts.
// Split-phase grid barrier: arrive right after stores drain; wait just
// before peer data is consumed; layer-0's xT-side GEMM runs in between.

__global__ __launch_bounds__(256, 1) void gru_persistent(
    const f16* __restrict__ xT, const f16* __restrict__ W3,
    const f16* __restrict__ wts,
    const float* __restrict__ bias0, const float* __restrict__ bhh0,
    const float* __restrict__ bih1,  const float* __restrict__ bhh1,
    const float* __restrict__ bih2,  const float* __restrict__ bhh2,
    f16* __restrict__ hb, float* __restrict__ out, unsigned* __restrict__ bar)
{
    __shared__ f16 wih_lds[3 * NKS_HH * 64 * 8];  // 49152 B (layer0 uses subset)
    __shared__ f16 whh_lds[3 * NKS_HH * 64 * 8];  // 49152 B

    const int bid   = blockIdx.x;
    const int layer = bid >> 5;       // 0..2
    const int slice = bid & 31;       // 0..31
    const int j0    = slice * 16;
    const int tid   = threadIdx.x;
    const int lane  = tid & 63;
    const int wid   = tid >> 6;
    const int b0    = wid * 16;
    const int jc    = lane & 15;
    const int kg    = lane >> 4;
    const int j     = j0 + jc;

    const int KIN = (layer == 0) ? KIN0 : HD;
    const int nksI = (layer == 0) ? NKS_I0 : NKS_HH;
    const f16* wih_g = (layer == 0) ? W3 : (wts + (size_t)(2 * layer - 1) * (G3 * HD));
    const f16* whh_g = wts + (size_t)(2 * layer) * (G3 * HD);

    // ---- stage weights into fragment-major LDS (once) ----
    for (int e = tid; e < 3 * nksI * 64; e += 256) {
        int le = e & 63;
        int ks = (e >> 6) % nksI;
        int g  = (e >> 6) / nksI;
        int row = j0 + (le & 15);
        int col = ks * 32 + (le >> 4) * 8;
        *(half8*)&wih_lds[(size_t)e * 8] =
            *(const half8*)(wih_g + (size_t)(g * HD + row) * KIN + col);
    }
    for (int e = tid; e < 3 * NKS_HH * 64; e += 256) {
        int le = e & 63;
        int ks = (e >> 6) % NKS_HH;
        int g  = (e >> 6) / NKS_HH;
        int row = j0 + (le & 15);
        int col = ks * 32 + (le >> 4) * 8;
        *(half8*)&whh_lds[(size_t)e * 8] =
            *(const half8*)(whh_g + (size_t)(g * HD + row) * HD + col);
    }

    const float* bih = (layer == 0) ? bias0 : ((layer == 1) ? bih1 : bih2);
    const float* bhh = (layer == 0) ? bhh0  : ((layer == 1) ? bhh1 : bhh2);
    const float bir = bih[j],          bhr = bhh[j];
    const float biz = bih[HD + j],     bhz = bhh[HD + j];
    const float bin = bih[2 * HD + j], bhn = bhh[2 * HD + j];

    const int HS = BATCH * HD;
    f16* hbase = hb + (size_t)layer * 2 * HS;
    const f16* hprev_base = (layer == 0) ? nullptr : (hb + (size_t)(layer - 1) * 2 * HS);

    // previous own-h for the z-blend, carried in registers
    float hpr[4];
    {
        const f16* hinit = hbase + 1 * HS;   // parity of t = -1
        #pragma unroll
        for (int rr = 0; rr < 4; ++rr)
            hpr[rr] = (float)hinit[(size_t)(b0 + kg * 4 + rr) * HD + j];
    }

    __syncthreads();

    const f16* fW = wih_lds + lane * 8;   // per-lane fragment base
    const f16* fH = whh_lds + lane * 8;

    for (int R = 0; R < XT_S; ++R) {
        const int t = R - layer;
        const bool active = (t >= 0) && (t < TLEN);

        f32x4 accR  = {0.f, 0.f, 0.f, 0.f};
        f32x4 accZ  = {0.f, 0.f, 0.f, 0.f};
        f32x4 accNi = {0.f, 0.f, 0.f, 0.f};
        f32x4 accNh = {0.f, 0.f, 0.f, 0.f};

        // ---- phase 1: layer-0 input-side GEMM (independent of peers) ----
        if (layer == 0 && active) {
            const f16* xb = xT + (size_t)(b0 + jc) * XT_STRIDE + (size_t)t * 64 + kg * 8;
            #pragma unroll
            for (int ks = 0; ks < NKS_I0; ++ks) {
                half8 a = *(const half8*)(xb + ks * 32);
                accR  = mfma16(a, *(const half8*)(fW + (0 * NKS_I0 + ks) * 512), accR);
                accZ  = mfma16(a, *(const half8*)(fW + (1 * NKS_I0 + ks) * 512), accZ);
                accNi = mfma16(a, *(const half8*)(fW + (2 * NKS_I0 + ks) * 512), accNi);
            }
        }

        // ---- phase 2: wait for all peers' previous round ----
        if (R > 0) {
            if (tid == 0) {
                const unsigned tgt = (unsigned)R * NBLOCKS;
                while (__hip_atomic_load(&bar[0], __ATOMIC_RELAXED,
                                         __HIP_MEMORY_SCOPE_AGENT) < tgt)
                    __builtin_amdgcn_s_sleep(1);
            }
            __syncthreads();
            asm volatile("" ::: "memory");
        }

        // ---- phase 3: batched prefetch + GEMMs + fused GRU epilogue ----
        if (active) {
            const f16* hold = hbase + ((t - 1) & 1) * HS;
            const f16* hbp  = hold + (size_t)(b0 + jc) * HD + kg * 8;

            half8 ah[NKS_HH];
            #pragma unroll
            for (int ks = 0; ks < NKS_HH; ++ks) ah[ks] = loadA_sc1(hbp + ks * 32);

            if (layer > 0) {
                const f16* xbp = hprev_base + (t & 1) * HS + (size_t)(b0 + jc) * HD + kg * 8;
                half8 ax[NKS_HH];
                #pragma unroll
                for (int ks = 0; ks < NKS_HH; ++ks) ax[ks] = loadA_sc1(xbp + ks * 32);
                #pragma unroll
                for (int ks = 0; ks < NKS_HH; ++ks) {
                    accR  = mfma16(ax[ks], *(const half8*)(fW + (0 * NKS_HH + ks) * 512), accR);
                    accZ  = mfma16(ax[ks], *(const half8*)(fW + (1 * NKS_HH + ks) * 512), accZ);
                    accNi = mfma16(ax[ks], *(const half8*)(fW + (2 * NKS_HH + ks) * 512), accNi);
                    accR  = mfma16(ah[ks], *(const half8*)(fH + (0 * NKS_HH + ks) * 512), accR);
                    accZ  = mfma16(ah[ks], *(const half8*)(fH + (1 * NKS_HH + ks) * 512), accZ);
                    accNh = mfma16(ah[ks], *(const half8*)(fH + (2 * NKS_HH + ks) * 512), accNh);
                }
            } else {
                #pragma unroll
                for (int ks = 0; ks < NKS_HH; ++ks) {
                    accR  = mfma16(ah[ks], *(const half8*)(fH + (0 * NKS_HH + ks) * 512), accR);
                    accZ  = mfma16(ah[ks], *(const half8*)(fH + (1 * NKS_HH + ks) * 512), accZ);
                    accNh = mfma16(ah[ks], *(const half8*)(fH + (2 * NKS_HH + ks) * 512), accNh);
                }
            }

            f16* hnew = hbase + (t & 1) * HS;
            #pragma unroll
            for (int rr = 0; rr < 4; ++rr) {
                int brow = b0 + kg * 4 + rr;   // C/D row = (lane>>4)*4 + reg
                float r = 1.f / (1.f + __expf(-(accR[rr] + bir + bhr)));
                float z = 1.f / (1.f + __expf(-(accZ[rr] + biz + bhz)));
                float nv = accNi[rr] + bin + r * (accNh[rr] + bhn);
                float e  = __expf(2.f * nv);
                float n  = 1.f - 2.f / (e + 1.f);   // tanh, safe at +/-inf
                float hv = (1.f - z) * n + z * hpr[rr];
                hpr[rr] = hv;
                // pack (j, j+1) f16 pair; even-jc lanes store u32 sc1
                float nbv = __shfl_xor(hv, 1);
                if (!(jc & 1)) {
                    unsigned short ua = __builtin_bit_cast(unsigned short, (f16)hv);
                    unsigned short ub = __builtin_bit_cast(unsigned short, (f16)nbv);
                    unsigned pk = (unsigned)ua | ((unsigned)ub << 16);
                    __hip_atomic_store((unsigned*)(hnew + (size_t)brow * HD + j), pk,
                                       __ATOMIC_RELAXED, __HIP_MEMORY_SCOPE_AGENT);
                }
                if (layer == 2) out[(size_t)t * HS + (size_t)brow * HD + j] = hv;
            }
        }

        // ---- phase 4: arrive (after stores drain via __syncthreads) ----
        if (R < XT_S - 1) {
            __syncthreads();
            if (tid == 0)
                __hip_atomic_fetch_add(&bar[0], 1u, __ATOMIC_RELAXED,
                                       __HIP_MEMORY_SCOPE_AGENT);
        }
    }
}

// ---------------- launch ----------------

extern "C" void kernel_launch(void* const* d_in, const int* in_sizes, int n_in,
                              void* d_out, int out_size, void* d_ws, size_t ws_size,
                              hipStream_t stream) {
    const float* x     = (const float*)d_in[0];
    const float* h1    = (const float*)d_in[1];
    const float* h2    = (const float*)d_in[2];
    const float* h3    = (const float*)d_in[3];
    const float* convw = (const float*)d_in[4];
    const float* convb = (const float*)d_in[5];
    const float* wih0  = (const float*)d_in[6];
    const float* whh0  = (const float*)d_in[7];
    const float* bih0  = (const float*)d_in[8];
    const float* bhh0  = (const float*)d_in[9];
    const float* wih1  = (const float*)d_in[10];
    const float* whh1  = (const float*)d_in[11];
    const float* bih1  = (const float*)d_in[12];
    const float* bhh1  = (const float*)d_in[13];
    const float* wih2  = (const float*)d_in[14];
    const float* whh2  = (const float*)d_in[15];
    const float* bih2  = (const float*)d_in[16];
    const float* bhh2  = (const float*)d_in[17];

    // workspace layout (16B-aligned)
    char* ws = (char*)d_ws;
    unsigned* bar  = (unsigned*)(ws + 0);      // 64 B
    f16*   W3    = (f16*)(ws + 64);            // 1536*192*2      = 589824
    float* bias0 = (float*)(ws + 589888);      // 1536*4          = 6144
    f16*   wts   = (f16*)(ws + 596032);        // 5*1536*512*2    = 7864320
    f16*   xT    = (f16*)(ws + 8460352);       // 64*258*64*2     = 2113536
    f16*   hb    = (f16*)(ws + 10573888);      // 6*64*512*2      = 393216

    fold_w3   <<<(G3 * KIN0 + 255) / 256, 256, 0, stream>>>(wih0, convw, W3);
    fold_bias0<<<(G3 * 64 + 255) / 256,   256, 0, stream>>>(wih0, convb, bih0, bias0);
    Ptr5 p5; p5.p[0] = whh0; p5.p[1] = wih1; p5.p[2] = whh1; p5.p[3] = wih2; p5.p[4] = whh2;
    cvt_weights<<<(5 * G3 * HD + 255) / 256, 256, 0, stream>>>(p5, wts);
    build_xt  <<<(BATCH * XT_S * 64 + 255) / 256, 256, 0, stream>>>(x, xT);
    init_h    <<<(BATCH * HD + 255) / 256, 256, 0, stream>>>(h1, h2, h3, hb, bar);

    gru_persistent<<<NBLOCKS, 256, 0, stream>>>(
        xT, W3, wts, bias0, bhh0, bih1, bhh1, bih2, bhh2,
        hb, (float*)d_out, bar);
}

// Round 5
// 2619.526 us; speedup vs baseline: 1.2091x; 1.2091x over previous
//
#include <hip/hip_runtime.h>
#include <hip/hip_fp16.h>

// Problem constants
#define BATCH 64
#define TLEN  256
#define HD    512
#define G3    1536          // 3*H
#define KIN0  192           // folded conv+proj K = 64 bins * 3 taps
#define XT_S  258           // padded time slots (t' = -1 .. 256)
#define XT_STRIDE (XT_S*64) // per-batch stride in xT (16512)
#define NBLOCKS 96
#define NKS_HH 16           // HD/32 k-steps
#define NKS_I0 6            // KIN0/32 k-steps

typedef _Float16 f16;
typedef unsigned long long u64;
typedef __attribute__((ext_vector_type(8))) _Float16 half8;
typedef __attribute__((ext_vector_type(4))) float    f32x4;

__device__ __forceinline__ f32x4 mfma16(half8 a, half8 b, f32x4 c) {
    return __builtin_amdgcn_mfma_f32_16x16x32_f16(a, b, c, 0, 0, 0);
}

// Device-coherent (MALL) 16B load as two relaxed agent-scope u64 atomic loads.
__device__ __forceinline__ half8 loadA_sc1(const f16* p) {
    union { u64 v[2]; half8 h; } u;
    const u64* q = (const u64*)p;
    u.v[0] = __hip_atomic_load(q,     __ATOMIC_RELAXED, __HIP_MEMORY_SCOPE_AGENT);
    u.v[1] = __hip_atomic_load(q + 1, __ATOMIC_RELAXED, __HIP_MEMORY_SCOPE_AGENT);
    return u.h;
}

// ---------------- setup kernels ----------------

__global__ void fold_w3(const float* __restrict__ wih0,
                        const float* __restrict__ convw,
                        f16* __restrict__ w3) {
    int idx = blockIdx.x * 256 + threadIdx.x;
    if (idx >= G3 * KIN0) return;
    int g  = idx / KIN0;
    int kk = idx % KIN0;
    int dt = kk >> 6;
    int i  = kk & 63;
    float s = 0.f;
    for (int dr = 0; dr < 3; ++dr) {
        int r = i - dr;
        if (r < 0 || r >= 62) continue;
        const float* wrow = wih0 + (size_t)g * 3968 + r;
        #pragma unroll 8
        for (int f = 0; f < 64; ++f)
            s += wrow[f * 62] * convw[f * 9 + dr * 3 + dt];
    }
    w3[(size_t)g * KIN0 + kk] = (f16)s;
}

// wave-per-row: bias0[g] = b_ih0[g] + sum_e wih0[g,e] * convb[e/62]
__global__ void fold_bias0(const float* __restrict__ wih0,
                           const float* __restrict__ convb,
                           const float* __restrict__ bih0,
                           float* __restrict__ bias0) {
    int w    = (blockIdx.x * 256 + threadIdx.x) >> 6;
    int lane = threadIdx.x & 63;
    if (w >= G3) return;
    const float* wrow = wih0 + (size_t)w * 3968;
    float s = 0.f;
    for (int e = lane; e < 3968; e += 64) s += wrow[e] * convb[e / 62];
    #pragma unroll
    for (int o = 32; o > 0; o >>= 1) s += __shfl_down(s, o);
    if (lane == 0) bias0[w] = s + bih0[w];
}

struct Ptr5 { const float* p[5]; };

__global__ void cvt_weights(Ptr5 src, f16* __restrict__ dst) {
    int idx = blockIdx.x * 256 + threadIdx.x;
    if (idx >= 5 * G3 * HD) return;
    int m = idx / (G3 * HD), off = idx % (G3 * HD);
    dst[idx] = (f16)src.p[m][off];
}

// xT[b][s][i] = x[b, i, s-1] with zero pad at s=0 and s=257
__global__ void build_xt(const float* __restrict__ x, f16* __restrict__ xt) {
    int idx = blockIdx.x * 256 + threadIdx.x;
    if (idx >= BATCH * XT_S * 64) return;
    int b = idx / (XT_S * 64);
    int rem = idx % (XT_S * 64);
    int s = rem / 64, i = rem & 63;
    float v = 0.f;
    if (s >= 1 && s <= 256) v = x[(size_t)b * (64 * TLEN) + (size_t)i * TLEN + (s - 1)];
    xt[idx] = (f16)v;
}

// h(-1) lives at parity slot 1; also zero the per-block flag lines.
__global__ void init_h(const float* __restrict__ h1, const float* __restrict__ h2,
                       const float* __restrict__ h3, f16* __restrict__ hbuf,
                       unsigned* __restrict__ flags) {
    int idx = blockIdx.x * 256 + threadIdx.x;
    const int HS = BATCH * HD;
    if (idx < NBLOCKS * 16) flags[idx] = 0u;
    if (idx >= HS) return;
    hbuf[1 * HS + idx] = (f16)h1[idx];
    hbuf[3 * HS + idx] = (f16)h2[idx];
    hbuf[5 * HS + idx] = (f16)h3[idx];
}

// ---------------- persistent diagonal-pipelined GRU ----------------
// Distributed flags: flags[bid*16] = number of completed rounds (own 64-B
// line per block, no RMW). Layer l at round R: pollA waits layers {l-1,l}
// flags >= R (data dep, per-wave parallel gather, self-release); pollB
// waits layer l+1 >= R just before overwriting the h parity slot
// (anti-dep, almost always already satisfied). No global counter.

__global__ __launch_bounds__(256, 1) void gru_persistent(
    const f16* __restrict__ xT, const f16* __restrict__ W3,
    const f16* __restrict__ wts,
    const float* __restrict__ bias0, const float* __restrict__ bhh0,
    const float* __restrict__ bih1,  const float* __restrict__ bhh1,
    const float* __restrict__ bih2,  const float* __restrict__ bhh2,
    f16* __restrict__ hb, float* __restrict__ out, unsigned* __restrict__ flags)
{
    __shared__ f16 wih_lds[3 * NKS_HH * 64 * 8];  // 49152 B (layer0 uses subset)
    __shared__ f16 whh_lds[3 * NKS_HH * 64 * 8];  // 49152 B

    const int bid   = blockIdx.x;
    const int layer = bid >> 5;       // 0..2
    const int slice = bid & 31;       // 0..31
    const int j0    = slice * 16;
    const int tid   = threadIdx.x;
    const int lane  = tid & 63;
    const int wid   = tid >> 6;
    const int b0    = wid * 16;
    const int jc    = lane & 15;
    const int kg    = lane >> 4;
    const int j     = j0 + jc;

    const int KIN = (layer == 0) ? KIN0 : HD;
    const int nksI = (layer == 0) ? NKS_I0 : NKS_HH;
    const f16* wih_g = (layer == 0) ? W3 : (wts + (size_t)(2 * layer - 1) * (G3 * HD));
    const f16* whh_g = wts + (size_t)(2 * layer) * (G3 * HD);

    // ---- stage weights into fragment-major LDS (once) ----
    for (int e = tid; e < 3 * nksI * 64; e += 256) {
        int le = e & 63;
        int ks = (e >> 6) % nksI;
        int g  = (e >> 6) / nksI;
        int row = j0 + (le & 15);
        int col = ks * 32 + (le >> 4) * 8;
        *(half8*)&wih_lds[(size_t)e * 8] =
            *(const half8*)(wih_g + (size_t)(g * HD + row) * KIN + col);
    }
    for (int e = tid; e < 3 * NKS_HH * 64; e += 256) {
        int le = e & 63;
        int ks = (e >> 6) % NKS_HH;
        int g  = (e >> 6) / NKS_HH;
        int row = j0 + (le & 15);
        int col = ks * 32 + (le >> 4) * 8;
        *(half8*)&whh_lds[(size_t)e * 8] =
            *(const half8*)(whh_g + (size_t)(g * HD + row) * HD + col);
    }

    const float* bih = (layer == 0) ? bias0 : ((layer == 1) ? bih1 : bih2);
    const float* bhh = (layer == 0) ? bhh0  : ((layer == 1) ? bhh1 : bhh2);
    const float bRs = bih[j] + bhh[j];
    const float bZs = bih[HD + j] + bhh[HD + j];
    const float bin = bih[2 * HD + j];
    const float bhn = bhh[2 * HD + j];

    const int HS = BATCH * HD;
    f16* hbase = hb + (size_t)layer * 2 * HS;
    const f16* hprev_base = (layer == 0) ? nullptr : (hb + (size_t)(layer - 1) * 2 * HS);

    // previous own-h for the z-blend, carried in registers
    float hpr[4];
    {
        const f16* hinit = hbase + 1 * HS;   // parity of t = -1
        #pragma unroll
        for (int rr = 0; rr < 4; ++rr)
            hpr[rr] = (float)hinit[(size_t)(b0 + kg * 4 + rr) * HD + j];
    }

    __syncthreads();

    const f16* fW = wih_lds + lane * 8;   // per-lane fragment base
    const f16* fH = whh_lds + lane * 8;

    // pollA flag index: lanes 0..31 -> own layer, 32..63 -> layer-1 (if any)
    const int fbA = (lane < 32) ? (layer * 32 + lane)
                                : ((layer > 0) ? ((layer - 1) * 32 + (lane - 32)) : -1);
    const unsigned* fpA = (fbA >= 0) ? (flags + (size_t)fbA * 16) : nullptr;
    const unsigned* fpB = (layer < 2 && lane < 32)
                        ? (flags + (size_t)((layer + 1) * 32 + lane) * 16) : nullptr;

    for (int R = 0; R < XT_S; ++R) {
        const int t = R - layer;
        const bool active = (t >= 0) && (t < TLEN);

        f32x4 aRx = {0.f,0.f,0.f,0.f}, aZx = {0.f,0.f,0.f,0.f}, aNi = {0.f,0.f,0.f,0.f};
        f32x4 aRh = {0.f,0.f,0.f,0.f}, aZh = {0.f,0.f,0.f,0.f}, aNh = {0.f,0.f,0.f,0.f};

        // ---- phase A: layer-0 input-side GEMM (peer-independent) ----
        if (layer == 0 && active) {
            const f16* xb = xT + (size_t)(b0 + jc) * XT_STRIDE + (size_t)t * 64 + kg * 8;
            #pragma unroll
            for (int ks = 0; ks < NKS_I0; ++ks) {
                half8 a = *(const half8*)(xb + ks * 32);
                aRx = mfma16(a, *(const half8*)(fW + (0 * NKS_I0 + ks) * 512), aRx);
                aZx = mfma16(a, *(const half8*)(fW + (1 * NKS_I0 + ks) * 512), aZx);
                aNi = mfma16(a, *(const half8*)(fW + (2 * NKS_I0 + ks) * 512), aNi);
            }
        }

        // ---- pollA: wait for layers {l-1, l} completed >= R (per-wave) ----
        if (fpA)
            while (__hip_atomic_load(fpA, __ATOMIC_RELAXED, __HIP_MEMORY_SCOPE_AGENT)
                   < (unsigned)R) {}
        asm volatile("" ::: "memory");

        float hv[4];
        if (active) {
            const f16* hold = hbase + ((t - 1) & 1) * HS;
            const f16* hbp  = hold + (size_t)(b0 + jc) * HD + kg * 8;

            half8 ah[NKS_HH];
            #pragma unroll
            for (int ks = 0; ks < NKS_HH; ++ks) ah[ks] = loadA_sc1(hbp + ks * 32);

            if (layer > 0) {
                const f16* xbp = hprev_base + (t & 1) * HS + (size_t)(b0 + jc) * HD + kg * 8;
                half8 ax[NKS_HH];
                #pragma unroll
                for (int ks = 0; ks < NKS_HH; ++ks) ax[ks] = loadA_sc1(xbp + ks * 32);
                #pragma unroll
                for (int ks = 0; ks < NKS_HH; ++ks) {
                    aRx = mfma16(ax[ks], *(const half8*)(fW + (0 * NKS_HH + ks) * 512), aRx);
                    aZx = mfma16(ax[ks], *(const half8*)(fW + (1 * NKS_HH + ks) * 512), aZx);
                    aNi = mfma16(ax[ks], *(const half8*)(fW + (2 * NKS_HH + ks) * 512), aNi);
                    aRh = mfma16(ah[ks], *(const half8*)(fH + (0 * NKS_HH + ks) * 512), aRh);
                    aZh = mfma16(ah[ks], *(const half8*)(fH + (1 * NKS_HH + ks) * 512), aZh);
                    aNh = mfma16(ah[ks], *(const half8*)(fH + (2 * NKS_HH + ks) * 512), aNh);
                }
            } else {
                #pragma unroll
                for (int ks = 0; ks < NKS_HH; ++ks) {
                    aRh = mfma16(ah[ks], *(const half8*)(fH + (0 * NKS_HH + ks) * 512), aRh);
                    aZh = mfma16(ah[ks], *(const half8*)(fH + (1 * NKS_HH + ks) * 512), aZh);
                    aNh = mfma16(ah[ks], *(const half8*)(fH + (2 * NKS_HH + ks) * 512), aNh);
                }
            }

            #pragma unroll
            for (int rr = 0; rr < 4; ++rr) {
                float r = 1.f / (1.f + __expf(-(aRx[rr] + aRh[rr] + bRs)));
                float z = 1.f / (1.f + __expf(-(aZx[rr] + aZh[rr] + bZs)));
                float nv = aNi[rr] + bin + r * (aNh[rr] + bhn);
                float e  = __expf(2.f * nv);
                float n  = 1.f - 2.f / (e + 1.f);   // tanh, safe at +/-inf
                hv[rr] = (1.f - z) * n + z * hpr[rr];
                hpr[rr] = hv[rr];
            }
        }

        // ---- pollB: anti-dep on layer l+1 (guards h slot overwrite) ----
        if (active && layer < 2) {
            if (fpB)
                while (__hip_atomic_load(fpB, __ATOMIC_RELAXED, __HIP_MEMORY_SCOPE_AGENT)
                       < (unsigned)R) {}
            asm volatile("" ::: "memory");
        }

        // ---- h stores (packed u64, quarter the requests) ----
        if (active) {
            f16* hnew = hbase + (t & 1) * HS;
            #pragma unroll
            for (int rr = 0; rr < 4; ++rr) {
                int brow = b0 + kg * 4 + rr;   // C/D row = (lane>>4)*4 + reg
                float nbv = __shfl_xor(hv[rr], 1);
                unsigned short ua = __builtin_bit_cast(unsigned short, (f16)hv[rr]);
                unsigned short ub = __builtin_bit_cast(unsigned short, (f16)nbv);
                unsigned pk = (unsigned)ua | ((unsigned)ub << 16);   // (j, j^1) in order on even jc
                unsigned pk2 = __shfl_xor(pk, 2);
                if ((jc & 3) == 0) {
                    u64 val = (u64)pk | ((u64)pk2 << 32);
                    __hip_atomic_store((u64*)(hnew + (size_t)brow * HD + j), val,
                                       __ATOMIC_RELAXED, __HIP_MEMORY_SCOPE_AGENT);
                }
            }
        }

        // ---- publish (after all waves' stores drained) ----
        __syncthreads();
        if (tid == 0)
            __hip_atomic_store(flags + (size_t)bid * 16, (unsigned)(R + 1),
                               __ATOMIC_RELAXED, __HIP_MEMORY_SCOPE_AGENT);

        // ---- out stores after publish (off the flag critical path) ----
        if (layer == 2 && active) {
            #pragma unroll
            for (int rr = 0; rr < 4; ++rr) {
                int brow = b0 + kg * 4 + rr;
                out[(size_t)t * HS + (size_t)brow * HD + j] = hv[rr];
            }
        }
    }
}

// ---------------- launch ----------------

extern "C" void kernel_launch(void* const* d_in, const int* in_sizes, int n_in,
                              void* d_out, int out_size, void* d_ws, size_t ws_size,
                              hipStream_t stream) {
    const float* x     = (const float*)d_in[0];
    const float* h1    = (const float*)d_in[1];
    const float* h2    = (const float*)d_in[2];
    const float* h3    = (const float*)d_in[3];
    const float* convw = (const float*)d_in[4];
    const float* convb = (const float*)d_in[5];
    const float* wih0  = (const float*)d_in[6];
    const float* whh0  = (const float*)d_in[7];
    const float* bih0  = (const float*)d_in[8];
    const float* bhh0  = (const float*)d_in[9];
    const float* wih1  = (const float*)d_in[10];
    const float* whh1  = (const float*)d_in[11];
    const float* bih1  = (const float*)d_in[12];
    const float* bhh1  = (const float*)d_in[13];
    const float* wih2  = (const float*)d_in[14];
    const float* whh2  = (const float*)d_in[15];
    const float* bih2  = (const float*)d_in[16];
    const float* bhh2  = (const float*)d_in[17];

    // workspace layout (16B-aligned)
    char* ws = (char*)d_ws;
    unsigned* flags = (unsigned*)(ws + 0);     // 96*64 B = 6144 (padded 8192)
    f16*   W3    = (f16*)(ws + 8192);          // 1536*192*2      = 589824
    float* bias0 = (float*)(ws + 598016);      // 1536*4          = 6144
    f16*   wts   = (f16*)(ws + 604160);        // 5*1536*512*2    = 7864320
    f16*   xT    = (f16*)(ws + 8468480);       // 64*258*64*2     = 2113536
    f16*   hb    = (f16*)(ws + 10582016);      // 6*64*512*2      = 393216

    fold_w3   <<<(G3 * KIN0 + 255) / 256, 256, 0, stream>>>(wih0, convw, W3);
    fold_bias0<<<(G3 * 64 + 255) / 256,   256, 0, stream>>>(wih0, convb, bih0, bias0);
    Ptr5 p5; p5.p[0] = whh0; p5.p[1] = wih1; p5.p[2] = whh1; p5.p[3] = wih2; p5.p[4] = whh2;
    cvt_weights<<<(5 * G3 * HD + 255) / 256, 256, 0, stream>>>(p5, wts);
    build_xt  <<<(BATCH * XT_S * 64 + 255) / 256, 256, 0, stream>>>(x, xT);
    init_h    <<<(BATCH * HD + 255) / 256, 256, 0, stream>>>(h1, h2, h3, hb, flags);

    gru_persistent<<<NBLOCKS, 256, 0, stream>>>(
        xT, W3, wts, bias0, bhh0, bih1, bhh1, bih2, bhh2,
        hb, (float*)d_out, flags);
}

// Round 6
// 1836.789 us; speedup vs baseline: 1.7243x; 1.4261x over previous
//
#include <hip/hip_runtime.h>
#include <hip/hip_fp16.h>

// Problem constants
#define BATCH 64
#define TLEN  256
#define HD    512
#define G3    1536          // 3*H
#define KIN0  192           // folded conv+proj K = 64 bins * 3 taps
#define XT_S  258           // padded time slots (t' = -1 .. 256)
#define XT_STRIDE (XT_S*64) // per-batch stride in xT (16512)
#define NBLOCKS 96
#define NKS_HH 16           // HD/32 k-steps
#define NKS_I0 6            // KIN0/32 k-steps

typedef _Float16 f16;
typedef unsigned long long u64;
typedef __attribute__((ext_vector_type(8))) _Float16 half8;
typedef __attribute__((ext_vector_type(4))) float    f32x4;

__device__ __forceinline__ f32x4 mfma16(half8 a, half8 b, f32x4 c) {
    return __builtin_amdgcn_mfma_f32_16x16x32_f16(a, b, c, 0, 0, 0);
}

// Issue a device-coherent (MALL) 16B load WITHOUT waiting: plain pipelined
// global_load_dwordx4 with sc0 sc1 (bypass L1/L2, served at the coherence
// point). Result must not be consumed before WAIT_VM0().
#define LD16(dst, base, OFF)                                                  \
    asm volatile("global_load_dwordx4 %0, %1, off offset:" #OFF " sc0 sc1"    \
                 : "=v"(dst) : "v"(base))

#define WAIT_VM0()                                         \
    do {                                                   \
        asm volatile("s_waitcnt vmcnt(0)" ::: "memory");   \
        __builtin_amdgcn_sched_barrier(0);                 \
    } while (0)

// ---------------- setup kernels ----------------

__global__ void fold_w3(const float* __restrict__ wih0,
                        const float* __restrict__ convw,
                        f16* __restrict__ w3) {
    int idx = blockIdx.x * 256 + threadIdx.x;
    if (idx >= G3 * KIN0) return;
    int g  = idx / KIN0;
    int kk = idx % KIN0;
    int dt = kk >> 6;
    int i  = kk & 63;
    float s = 0.f;
    for (int dr = 0; dr < 3; ++dr) {
        int r = i - dr;
        if (r < 0 || r >= 62) continue;
        const float* wrow = wih0 + (size_t)g * 3968 + r;
        #pragma unroll 8
        for (int f = 0; f < 64; ++f)
            s += wrow[f * 62] * convw[f * 9 + dr * 3 + dt];
    }
    w3[(size_t)g * KIN0 + kk] = (f16)s;
}

// wave-per-row: bias0[g] = b_ih0[g] + sum_e wih0[g,e] * convb[e/62]
__global__ void fold_bias0(const float* __restrict__ wih0,
                           const float* __restrict__ convb,
                           const float* __restrict__ bih0,
                           float* __restrict__ bias0) {
    int w    = (blockIdx.x * 256 + threadIdx.x) >> 6;
    int lane = threadIdx.x & 63;
    if (w >= G3) return;
    const float* wrow = wih0 + (size_t)w * 3968;
    float s = 0.f;
    for (int e = lane; e < 3968; e += 64) s += wrow[e] * convb[e / 62];
    #pragma unroll
    for (int o = 32; o > 0; o >>= 1) s += __shfl_down(s, o);
    if (lane == 0) bias0[w] = s + bih0[w];
}

struct Ptr5 { const float* p[5]; };

__global__ void cvt_weights(Ptr5 src, f16* __restrict__ dst) {
    int idx = blockIdx.x * 256 + threadIdx.x;
    if (idx >= 5 * G3 * HD) return;
    int m = idx / (G3 * HD), off = idx % (G3 * HD);
    dst[idx] = (f16)src.p[m][off];
}

// xT[b][s][i] = x[b, i, s-1] with zero pad at s=0 and s=257
__global__ void build_xt(const float* __restrict__ x, f16* __restrict__ xt) {
    int idx = blockIdx.x * 256 + threadIdx.x;
    if (idx >= BATCH * XT_S * 64) return;
    int b = idx / (XT_S * 64);
    int rem = idx % (XT_S * 64);
    int s = rem / 64, i = rem & 63;
    float v = 0.f;
    if (s >= 1 && s <= 256) v = x[(size_t)b * (64 * TLEN) + (size_t)i * TLEN + (s - 1)];
    xt[idx] = (f16)v;
}

// h(-1) lives at parity slot 1; also zero the per-block flag lines.
__global__ void init_h(const float* __restrict__ h1, const float* __restrict__ h2,
                       const float* __restrict__ h3, f16* __restrict__ hbuf,
                       unsigned* __restrict__ flags) {
    int idx = blockIdx.x * 256 + threadIdx.x;
    const int HS = BATCH * HD;
    if (idx < NBLOCKS * 16) flags[idx] = 0u;
    if (idx >= HS) return;
    hbuf[1 * HS + idx] = (f16)h1[idx];
    hbuf[3 * HS + idx] = (f16)h2[idx];
    hbuf[5 * HS + idx] = (f16)h3[idx];
}

// ---------------- persistent diagonal-pipelined GRU ----------------
// Distributed flags: flags[bid*16] = number of completed rounds. Layer l at
// round R waits layers {l-1,l} >= R (data dep), polls {l+1} >= R before
// overwriting its h parity slot (anti-dep, overlapped with A-loads).
// A-operands are fetched with batched asm sc0sc1 loads: issue all, wait once.

__global__ __launch_bounds__(256, 1) void gru_persistent(
    const f16* __restrict__ xT, const f16* __restrict__ W3,
    const f16* __restrict__ wts,
    const float* __restrict__ bias0, const float* __restrict__ bhh0,
    const float* __restrict__ bih1,  const float* __restrict__ bhh1,
    const float* __restrict__ bih2,  const float* __restrict__ bhh2,
    f16* __restrict__ hb, float* __restrict__ out, unsigned* __restrict__ flags)
{
    __shared__ f16 wih_lds[3 * NKS_HH * 64 * 8];  // 49152 B (layer0 uses subset)
    __shared__ f16 whh_lds[3 * NKS_HH * 64 * 8];  // 49152 B

    const int bid   = blockIdx.x;
    const int layer = bid >> 5;       // 0..2
    const int slice = bid & 31;       // 0..31
    const int j0    = slice * 16;
    const int tid   = threadIdx.x;
    const int lane  = tid & 63;
    const int wid   = tid >> 6;
    const int b0    = wid * 16;
    const int jc    = lane & 15;
    const int kg    = lane >> 4;
    const int j     = j0 + jc;

    const int KIN = (layer == 0) ? KIN0 : HD;
    const int nksI = (layer == 0) ? NKS_I0 : NKS_HH;
    const f16* wih_g = (layer == 0) ? W3 : (wts + (size_t)(2 * layer - 1) * (G3 * HD));
    const f16* whh_g = wts + (size_t)(2 * layer) * (G3 * HD);

    // ---- stage weights into fragment-major LDS (once) ----
    for (int e = tid; e < 3 * nksI * 64; e += 256) {
        int le = e & 63;
        int ks = (e >> 6) % nksI;
        int g  = (e >> 6) / nksI;
        int row = j0 + (le & 15);
        int col = ks * 32 + (le >> 4) * 8;
        *(half8*)&wih_lds[(size_t)e * 8] =
            *(const half8*)(wih_g + (size_t)(g * HD + row) * KIN + col);
    }
    for (int e = tid; e < 3 * NKS_HH * 64; e += 256) {
        int le = e & 63;
        int ks = (e >> 6) % NKS_HH;
        int g  = (e >> 6) / NKS_HH;
        int row = j0 + (le & 15);
        int col = ks * 32 + (le >> 4) * 8;
        *(half8*)&whh_lds[(size_t)e * 8] =
            *(const half8*)(whh_g + (size_t)(g * HD + row) * HD + col);
    }

    const float* bih = (layer == 0) ? bias0 : ((layer == 1) ? bih1 : bih2);
    const float* bhh = (layer == 0) ? bhh0  : ((layer == 1) ? bhh1 : bhh2);
    const float bRs = bih[j] + bhh[j];
    const float bZs = bih[HD + j] + bhh[HD + j];
    const float bin = bih[2 * HD + j];
    const float bhn = bhh[2 * HD + j];

    const int HS = BATCH * HD;
    f16* hbase = hb + (size_t)layer * 2 * HS;
    const f16* hprev_base = (layer == 0) ? nullptr : (hb + (size_t)(layer - 1) * 2 * HS);

    // previous own-h for the z-blend, carried in registers
    float hpr[4];
    {
        const f16* hinit = hbase + 1 * HS;   // parity of t = -1
        #pragma unroll
        for (int rr = 0; rr < 4; ++rr)
            hpr[rr] = (float)hinit[(size_t)(b0 + kg * 4 + rr) * HD + j];
    }

    __syncthreads();

    const f16* fW = wih_lds + lane * 8;   // per-lane fragment base
    const f16* fH = whh_lds + lane * 8;

    // pollA flag index: lanes 0..31 -> own layer, 32..63 -> layer-1 (if any)
    const int fbA = (lane < 32) ? (layer * 32 + lane)
                                : ((layer > 0) ? ((layer - 1) * 32 + (lane - 32)) : -1);
    const unsigned* fpA = (fbA >= 0) ? (flags + (size_t)fbA * 16) : nullptr;
    const unsigned* fpB = (layer < 2 && lane < 32)
                        ? (flags + (size_t)((layer + 1) * 32 + lane) * 16) : nullptr;

    for (int R = 0; R < XT_S; ++R) {
        const int t = R - layer;
        const bool active = (t >= 0) && (t < TLEN);

        f32x4 aRx = {0.f,0.f,0.f,0.f}, aZx = {0.f,0.f,0.f,0.f}, aNi = {0.f,0.f,0.f,0.f};
        f32x4 aRh = {0.f,0.f,0.f,0.f}, aZh = {0.f,0.f,0.f,0.f}, aNh = {0.f,0.f,0.f,0.f};

        // ---- phase A: layer-0 input-side GEMM (peer-independent) ----
        if (layer == 0 && active) {
            const f16* xb = xT + (size_t)(b0 + jc) * XT_STRIDE + (size_t)t * 64 + kg * 8;
            #pragma unroll
            for (int ks = 0; ks < NKS_I0; ++ks) {
                half8 a = *(const half8*)(xb + ks * 32);
                aRx = mfma16(a, *(const half8*)(fW + (0 * NKS_I0 + ks) * 512), aRx);
                aZx = mfma16(a, *(const half8*)(fW + (1 * NKS_I0 + ks) * 512), aZx);
                aNi = mfma16(a, *(const half8*)(fW + (2 * NKS_I0 + ks) * 512), aNi);
            }
        }

        // ---- pollA: wait for layers {l-1, l} completed >= R (per-wave) ----
        if (fpA)
            while (__hip_atomic_load(fpA, __ATOMIC_RELAXED, __HIP_MEMORY_SCOPE_AGENT)
                   < (unsigned)R) {}
        asm volatile("" ::: "memory");

        float hv[4];
        if (active) {
            const f16* hold = hbase + ((t - 1) & 1) * HS;
            const f16* hbp  = hold + (size_t)(b0 + jc) * HD + kg * 8;

            half8 ah[NKS_HH];
            // issue all own-h loads (no wait)
            LD16(ah[0],  hbp, 0);    LD16(ah[1],  hbp, 64);
            LD16(ah[2],  hbp, 128);  LD16(ah[3],  hbp, 192);
            LD16(ah[4],  hbp, 256);  LD16(ah[5],  hbp, 320);
            LD16(ah[6],  hbp, 384);  LD16(ah[7],  hbp, 448);
            LD16(ah[8],  hbp, 512);  LD16(ah[9],  hbp, 576);
            LD16(ah[10], hbp, 640);  LD16(ah[11], hbp, 704);
            LD16(ah[12], hbp, 768);  LD16(ah[13], hbp, 832);
            LD16(ah[14], hbp, 896);  LD16(ah[15], hbp, 960);

            if (layer > 0) {
                const f16* xbp = hprev_base + (t & 1) * HS + (size_t)(b0 + jc) * HD + kg * 8;
                half8 ax[NKS_HH];
                LD16(ax[0],  xbp, 0);    LD16(ax[1],  xbp, 64);
                LD16(ax[2],  xbp, 128);  LD16(ax[3],  xbp, 192);
                LD16(ax[4],  xbp, 256);  LD16(ax[5],  xbp, 320);
                LD16(ax[6],  xbp, 384);  LD16(ax[7],  xbp, 448);
                LD16(ax[8],  xbp, 512);  LD16(ax[9],  xbp, 576);
                LD16(ax[10], xbp, 640);  LD16(ax[11], xbp, 704);
                LD16(ax[12], xbp, 768);  LD16(ax[13], xbp, 832);
                LD16(ax[14], xbp, 896);  LD16(ax[15], xbp, 960);

                // ---- pollB overlapped with the loads in flight ----
                if (fpB)
                    while (__hip_atomic_load(fpB, __ATOMIC_RELAXED,
                                             __HIP_MEMORY_SCOPE_AGENT) < (unsigned)R) {}

                WAIT_VM0();
                #pragma unroll
                for (int ks = 0; ks < NKS_HH; ++ks) {
                    aRx = mfma16(ax[ks], *(const half8*)(fW + (0 * NKS_HH + ks) * 512), aRx);
                    aZx = mfma16(ax[ks], *(const half8*)(fW + (1 * NKS_HH + ks) * 512), aZx);
                    aNi = mfma16(ax[ks], *(const half8*)(fW + (2 * NKS_HH + ks) * 512), aNi);
                    aRh = mfma16(ah[ks], *(const half8*)(fH + (0 * NKS_HH + ks) * 512), aRh);
                    aZh = mfma16(ah[ks], *(const half8*)(fH + (1 * NKS_HH + ks) * 512), aZh);
                    aNh = mfma16(ah[ks], *(const half8*)(fH + (2 * NKS_HH + ks) * 512), aNh);
                }
            } else {
                // ---- pollB overlapped with the loads in flight ----
                if (fpB)
                    while (__hip_atomic_load(fpB, __ATOMIC_RELAXED,
                                             __HIP_MEMORY_SCOPE_AGENT) < (unsigned)R) {}

                WAIT_VM0();
                #pragma unroll
                for (int ks = 0; ks < NKS_HH; ++ks) {
                    aRh = mfma16(ah[ks], *(const half8*)(fH + (0 * NKS_HH + ks) * 512), aRh);
                    aZh = mfma16(ah[ks], *(const half8*)(fH + (1 * NKS_HH + ks) * 512), aZh);
                    aNh = mfma16(ah[ks], *(const half8*)(fH + (2 * NKS_HH + ks) * 512), aNh);
                }
            }

            #pragma unroll
            for (int rr = 0; rr < 4; ++rr) {
                float r = 1.f / (1.f + __expf(-(aRx[rr] + aRh[rr] + bRs)));
                float z = 1.f / (1.f + __expf(-(aZx[rr] + aZh[rr] + bZs)));
                float nv = aNi[rr] + bin + r * (aNh[rr] + bhn);
                float e  = __expf(2.f * nv);
                float n  = 1.f - 2.f / (e + 1.f);   // tanh, safe at +/-inf
                hv[rr] = (1.f - z) * n + z * hpr[rr];
                hpr[rr] = hv[rr];
            }

            // ---- h stores (packed u64) ----
            f16* hnew = hbase + (t & 1) * HS;
            #pragma unroll
            for (int rr = 0; rr < 4; ++rr) {
                int brow = b0 + kg * 4 + rr;   // C/D row = (lane>>4)*4 + reg
                float nbv = __shfl_xor(hv[rr], 1);
                unsigned short ua = __builtin_bit_cast(unsigned short, (f16)hv[rr]);
                unsigned short ub = __builtin_bit_cast(unsigned short, (f16)nbv);
                unsigned pk = (unsigned)ua | ((unsigned)ub << 16);
                unsigned pk2 = __shfl_xor(pk, 2);
                if ((jc & 3) == 0) {
                    u64 val = (u64)pk | ((u64)pk2 << 32);
                    __hip_atomic_store((u64*)(hnew + (size_t)brow * HD + j), val,
                                       __ATOMIC_RELAXED, __HIP_MEMORY_SCOPE_AGENT);
                }
            }
        }

        // ---- publish (after all waves' stores drained) ----
        __syncthreads();
        if (tid == 0)
            __hip_atomic_store(flags + (size_t)bid * 16, (unsigned)(R + 1),
                               __ATOMIC_RELAXED, __HIP_MEMORY_SCOPE_AGENT);

        // ---- out stores after publish (off the flag critical path) ----
        if (layer == 2 && active) {
            #pragma unroll
            for (int rr = 0; rr < 4; ++rr) {
                int brow = b0 + kg * 4 + rr;
                out[(size_t)t * HS + (size_t)brow * HD + j] = hv[rr];
            }
        }
    }
}

// ---------------- launch ----------------

extern "C" void kernel_launch(void* const* d_in, const int* in_sizes, int n_in,
                              void* d_out, int out_size, void* d_ws, size_t ws_size,
                              hipStream_t stream) {
    const float* x     = (const float*)d_in[0];
    const float* h1    = (const float*)d_in[1];
    const float* h2    = (const float*)d_in[2];
    const float* h3    = (const float*)d_in[3];
    const float* convw = (const float*)d_in[4];
    const float* convb = (const float*)d_in[5];
    const float* wih0  = (const float*)d_in[6];
    const float* whh0  = (const float*)d_in[7];
    const float* bih0  = (const float*)d_in[8];
    const float* bhh0  = (const float*)d_in[9];
    const float* wih1  = (const float*)d_in[10];
    const float* whh1  = (const float*)d_in[11];
    const float* bih1  = (const float*)d_in[12];
    const float* bhh1  = (const float*)d_in[13];
    const float* wih2  = (const float*)d_in[14];
    const float* whh2  = (const float*)d_in[15];
    const float* bih2  = (const float*)d_in[16];
    const float* bhh2  = (const float*)d_in[17];

    // workspace layout (16B-aligned)
    char* ws = (char*)d_ws;
    unsigned* flags = (unsigned*)(ws + 0);     // 96*64 B = 6144 (padded 8192)
    f16*   W3    = (f16*)(ws + 8192);          // 1536*192*2      = 589824
    float* bias0 = (float*)(ws + 598016);      // 1536*4          = 6144
    f16*   wts   = (f16*)(ws + 604160);        // 5*1536*512*2    = 7864320
    f16*   xT    = (f16*)(ws + 8468480);       // 64*258*64*2     = 2113536
    f16*   hb    = (f16*)(ws + 10582016);      // 6*64*512*2      = 393216

    fold_w3   <<<(G3 * KIN0 + 255) / 256, 256, 0, stream>>>(wih0, convw, W3);
    fold_bias0<<<(G3 * 64 + 255) / 256,   256, 0, stream>>>(wih0, convb, bih0, bias0);
    Ptr5 p5; p5.p[0] = whh0; p5.p[1] = wih1; p5.p[2] = whh1; p5.p[3] = wih2; p5.p[4] = whh2;
    cvt_weights<<<(5 * G3 * HD + 255) / 256, 256, 0, stream>>>(p5, wts);
    build_xt  <<<(BATCH * XT_S * 64 + 255) / 256, 256, 0, stream>>>(x, xT);
    init_h    <<<(BATCH * HD + 255) / 256, 256, 0, stream>>>(h1, h2, h3, hb, flags);

    gru_persistent<<<NBLOCKS, 256, 0, stream>>>(
        xT, W3, wts, bias0, bhh0, bih1, bhh1, bih2, bhh2,
        hb, (float*)d_out, flags);
}